// Round 1
// baseline (438.953 us; speedup 1.0000x reference)
//
#include <hip/hip_runtime.h>
#include <hip/hip_bf16.h>

// Conv2d: data [32,1,224,224] f32, weight [64,1,3,3] f32 -> out [32,64,222,222] f32
// VALID padding, stride 1, cross-correlation (no kernel flip).
// Write-BW bound: 403.7 MB out. Each thread: one (b, y, 2x) position, all 64 channels,
// reusing a 3x4 input patch held in registers. float2 loads/stores (8B-aligned provable).

#define IN_H 224
#define IN_W 224
#define OUT_H 222
#define OUT_W 222
#define OUT_C 64
#define BATCH 32
#define XPAIRS (OUT_W / 2)   // 111

__global__ __launch_bounds__(256) void conv3x3_kernel(
    const float* __restrict__ in, const float* __restrict__ wt,
    float* __restrict__ out) {
  const int tid = blockIdx.x * blockDim.x + threadIdx.x;
  const int total = BATCH * OUT_H * XPAIRS;
  if (tid >= total) return;

  const int xp = tid % XPAIRS;
  const int t  = tid / XPAIRS;
  const int y  = t % OUT_H;
  const int b  = t / OUT_H;
  const int x  = xp * 2;

  // Input patch: rows y..y+2, cols x..x+3. x even -> float2 loads are 8B aligned.
  const float* ip = in + ((size_t)b * IN_H + y) * IN_W + x;
  float2 r0a = *(const float2*)(ip);
  float2 r0b = *(const float2*)(ip + 2);
  float2 r1a = *(const float2*)(ip + IN_W);
  float2 r1b = *(const float2*)(ip + IN_W + 2);
  float2 r2a = *(const float2*)(ip + 2 * IN_W);
  float2 r2b = *(const float2*)(ip + 2 * IN_W + 2);

  const float i00 = r0a.x, i01 = r0a.y, i02 = r0b.x, i03 = r0b.y;
  const float i10 = r1a.x, i11 = r1a.y, i12 = r1b.x, i13 = r1b.y;
  const float i20 = r2a.x, i21 = r2a.y, i22 = r2b.x, i23 = r2b.y;

  // Output pointer for channel 0; channel stride = OUT_H*OUT_W (=49284, %4==0).
  float* op = out + ((size_t)b * OUT_C) * (OUT_H * OUT_W)
                  + (size_t)y * OUT_W + x;

  #pragma unroll 4
  for (int ch = 0; ch < OUT_C; ++ch) {
    const float* w = wt + ch * 9;   // wave-uniform -> s_load into SGPRs
    const float w0 = w[0], w1 = w[1], w2 = w[2];
    const float w3 = w[3], w4 = w[4], w5 = w[5];
    const float w6 = w[6], w7 = w[7], w8 = w[8];

    float o0 = i00 * w0;
    float o1 = i01 * w0;
    o0 = fmaf(i01, w1, o0);  o1 = fmaf(i02, w1, o1);
    o0 = fmaf(i02, w2, o0);  o1 = fmaf(i03, w2, o1);
    o0 = fmaf(i10, w3, o0);  o1 = fmaf(i11, w3, o1);
    o0 = fmaf(i11, w4, o0);  o1 = fmaf(i12, w4, o1);
    o0 = fmaf(i12, w5, o0);  o1 = fmaf(i13, w5, o1);
    o0 = fmaf(i20, w6, o0);  o1 = fmaf(i21, w6, o1);
    o0 = fmaf(i21, w7, o0);  o1 = fmaf(i22, w7, o1);
    o0 = fmaf(i22, w8, o0);  o1 = fmaf(i23, w8, o1);

    *(float2*)op = make_float2(o0, o1);
    op += OUT_H * OUT_W;
  }
}

extern "C" void kernel_launch(void* const* d_in, const int* in_sizes, int n_in,
                              void* d_out, int out_size, void* d_ws, size_t ws_size,
                              hipStream_t stream) {
  const float* data   = (const float*)d_in[0];
  const float* weight = (const float*)d_in[1];
  float* out = (float*)d_out;

  const int total = BATCH * OUT_H * XPAIRS;   // 32*222*111 = 788544
  const int block = 256;
  const int grid  = (total + block - 1) / block;
  conv3x3_kernel<<<grid, block, 0, stream>>>(data, weight, out);
}

// Round 2
// 436.613 us; speedup vs baseline: 1.0054x; 1.0054x over previous
//
#include <hip/hip_runtime.h>
#include <hip/hip_bf16.h>

// Conv2d: data [32,1,224,224] f32, weight [64,1,3,3] f32 -> out [32,64,222,222] f32
// VALID, stride 1, cross-correlation. Write-BW bound (403.7 MB out).
//
// R1 lesson: per-thread loop over all 64 channels scattered the write stream
// across 64 plane-strided regions -> HBM row thrash, 920 GB/s. Fix: channel
// goes in the grid (wave-uniform -> weights in SGPRs); each thread computes
// 4 consecutive x outputs for 2 channels, so each wave emits contiguous
// ~1-2 KB write runs per plane and consecutive blocks write consecutive rows.

#define IN_H 224
#define IN_W 224
#define OUT_H 222
#define OUT_W 222
#define OUT_C 64
#define BATCH 32
#define XG 56                       // groups of 4 outputs along x (last group: 2)
#define PLANE (OUT_H * OUT_W)       // 49284
#define THREADS_PER_PLANE (OUT_H * XG)  // 12432

__global__ __launch_bounds__(256) void conv3x3_kernel(
    const float* __restrict__ in, const float* __restrict__ wt,
    float* __restrict__ out) {
  const int t = blockIdx.x * blockDim.x + threadIdx.x;
  if (t >= THREADS_PER_PLANE) return;
  const int xg = t % XG;
  const int y  = t / XG;
  const int x  = xg * 4;
  const int b  = blockIdx.z;
  const int ch0 = blockIdx.y * 2;            // wave-uniform channel pair

  // Input patch rows y..y+2, cols x..x+5. Base index b*50176 + y*224 + x,
  // all terms %4==0 -> float4 is 16B aligned; +4 float2 is 8B aligned.
  const float* ip = in + ((size_t)b * IN_H + y) * IN_W + x;
  const float4 a0 = *(const float4*)(ip);
  const float4 a1 = *(const float4*)(ip + IN_W);
  const float4 a2 = *(const float4*)(ip + 2 * IN_W);

  const bool full = (xg != XG - 1);          // tail group (x=220): only 2 outputs
  float e00 = 0.f, e01 = 0.f, e10 = 0.f, e11 = 0.f, e20 = 0.f, e21 = 0.f;
  if (full) {
    const float2 e0 = *(const float2*)(ip + 4);
    const float2 e1 = *(const float2*)(ip + IN_W + 4);
    const float2 e2 = *(const float2*)(ip + 2 * IN_W + 4);
    e00 = e0.x; e01 = e0.y; e10 = e1.x; e11 = e1.y; e20 = e2.x; e21 = e2.y;
  }

  const float rin[3][6] = {
    {a0.x, a0.y, a0.z, a0.w, e00, e01},
    {a1.x, a1.y, a1.z, a1.w, e10, e11},
    {a2.x, a2.y, a2.z, a2.w, e20, e21},
  };

  float* op = out + (size_t)(b * OUT_C + ch0) * PLANE + (size_t)y * OUT_W + x;

  #pragma unroll
  for (int c = 0; c < 2; ++c) {
    const float* w = wt + (ch0 + c) * 9;     // uniform address -> s_load / SGPRs
    float o[4] = {0.f, 0.f, 0.f, 0.f};
    #pragma unroll
    for (int r = 0; r < 3; ++r) {
      #pragma unroll
      for (int k = 0; k < 3; ++k) {
        const float wv = w[r * 3 + k];
        #pragma unroll
        for (int j = 0; j < 4; ++j)
          o[j] = fmaf(rin[r][j + k], wv, o[j]);
      }
    }
    // Output base: (b*64+ch)*49284 + y*222 + x -> even -> float2 8B aligned.
    *(float2*)(op)     = make_float2(o[0], o[1]);
    if (full)
      *(float2*)(op + 2) = make_float2(o[2], o[3]);
    op += PLANE;
  }
}

extern "C" void kernel_launch(void* const* d_in, const int* in_sizes, int n_in,
                              void* d_out, int out_size, void* d_ws, size_t ws_size,
                              hipStream_t stream) {
  const float* data   = (const float*)d_in[0];
  const float* weight = (const float*)d_in[1];
  float* out = (float*)d_out;

  dim3 grid((THREADS_PER_PLANE + 255) / 256, OUT_C / 2, BATCH);
  conv3x3_kernel<<<grid, 256, 0, stream>>>(data, weight, out);
}